// Round 5
// baseline (10407.645 us; speedup 1.0000x reference)
//
#include <hip/hip_runtime.h>
#include <math.h>

// Problem constants: B=4096, SORB=64, H=256, NELE=32 (alpha=16), 2 GRU layers
#define BB 4096
#define SS 64
#define HH 256
#define BT 16    // batch rows per workgroup -> 256 WGs
#define NT 256   // threads per workgroup; thread t owns hidden unit t
#define HP 260   // padded LDS row stride (16B-aligned, breaks bank conflicts)

__device__ __forceinline__ float sigmoidf_(float v) {
    return 1.0f / (1.0f + expf(-v));
}

// Output: harness maps complex64 -> float*, out_size = 4096 (== B) floats.
// Expected flat vector is the REAL PART of wf: out[i] = amp_i * cos(ph_i).
__global__ __launch_bounds__(NT, 1) void rnn_persist(
    const int*   __restrict__ x,     // (B, S) in {-1,+1}, int32
    const float* __restrict__ Wih0,  // (768, 2)
    const float* __restrict__ Whh0,  // (768, 256)
    const float* __restrict__ Wih1,  // (768, 256)
    const float* __restrict__ Whh1,  // (768, 256)
    const float* __restrict__ Wl,    // (2, 256)
    const float* __restrict__ bl,    // (2,)
    float* __restrict__ out)         // (B,) floats: real(wf)
{
    __shared__ float h0s[BT][HP];
    __shared__ float h1s[BT][HP];
    __shared__ float wls[2 * HH];
    __shared__ int   bitsS[BT][SS];

    const int t = threadIdx.x;
    const int row0 = blockIdx.x * BT;

    #pragma unroll
    for (int b = 0; b < BT; ++b) { h0s[b][t] = 0.f; h1s[b][t] = 0.f; }
    for (int i = t; i < 2 * HH; i += NT) wls[i] = Wl[i];
    for (int i = t; i < BT * SS; i += NT) {
        int b = i / SS, s = i - b * SS;
        bitsS[b][s] = (x[(row0 + b) * SS + s] > 0) ? 1 : 0;
    }

    // Layer-0 input gates: gi = Wih0[g, prevbit]; gate rows r->t, z->t+256, n->t+512
    const float gir0 = Wih0[(t         ) * 2 + 0], gir1 = Wih0[(t         ) * 2 + 1];
    const float giz0 = Wih0[(t +     HH) * 2 + 0], giz1 = Wih0[(t +     HH) * 2 + 1];
    const float gin0 = Wih0[(t + 2 * HH) * 2 + 0], gin1 = Wih0[(t + 2 * HH) * 2 + 1];
    const float bl0 = bl[0], bl1 = bl[1];

    const float4* w0r = (const float4*)(Whh0 + (t         ) * HH);
    const float4* w0z = (const float4*)(Whh0 + (t +     HH) * HH);
    const float4* w0n = (const float4*)(Whh0 + (t + 2 * HH) * HH);
    const float4* w1r = (const float4*)(Wih1 + (t         ) * HH);
    const float4* w1z = (const float4*)(Wih1 + (t +     HH) * HH);
    const float4* w1n = (const float4*)(Wih1 + (t + 2 * HH) * HH);
    const float4* w2r = (const float4*)(Whh1 + (t         ) * HH);
    const float4* w2z = (const float4*)(Whh1 + (t +     HH) * HH);
    const float4* w2n = (const float4*)(Whh1 + (t + 2 * HH) * HH);

    float amp = 1.f, ph = 0.f, nup = 0.f, ndn = 0.f;

    __syncthreads();

    for (int step = 0; step < SS; ++step) {
        // ---------------- layer 0: gh0 = h0 @ Whh0^T ----------------
        float aR[BT], aZ[BT], aN[BT];
        #pragma unroll
        for (int b = 0; b < BT; ++b) { aR[b] = 0.f; aZ[b] = 0.f; aN[b] = 0.f; }
        for (int k4 = 0; k4 < HH / 4; ++k4) {
            float4 wr = w0r[k4], wz = w0z[k4], wn = w0n[k4];
            #pragma unroll
            for (int b = 0; b < BT; ++b) {
                float4 h = *(const float4*)(&h0s[b][k4 * 4]);
                aR[b] += h.x * wr.x + h.y * wr.y + h.z * wr.z + h.w * wr.w;
                aZ[b] += h.x * wz.x + h.y * wz.y + h.z * wz.z + h.w * wz.w;
                aN[b] += h.x * wn.x + h.y * wn.y + h.z * wn.z + h.w * wn.w;
            }
        }
        __syncthreads();   // all reads of old h0 complete

        #pragma unroll
        for (int b = 0; b < BT; ++b) {
            float gr = 0.f, gz = 0.f, gn = 0.f;
            if (step > 0) {
                int c = bitsS[b][step - 1];
                gr = c ? gir1 : gir0;
                gz = c ? giz1 : giz0;
                gn = c ? gin1 : gin0;
            }
            float r = sigmoidf_(gr + aR[b]);
            float z = sigmoidf_(gz + aZ[b]);
            float n = tanhf(gn + r * aN[b]);
            h0s[b][t] = (1.f - z) * n + z * h0s[b][t];
        }
        __syncthreads();   // new h0 visible

        // ------- layer 1: gi1 = h0n @ Wih1^T ; gh1 = h1 @ Whh1^T -------
        float bR[BT], bZ[BT], bNi[BT], bNh[BT];
        #pragma unroll
        for (int b = 0; b < BT; ++b) { bR[b] = 0.f; bZ[b] = 0.f; bNi[b] = 0.f; bNh[b] = 0.f; }
        for (int k4 = 0; k4 < HH / 4; ++k4) {
            float4 ar = w1r[k4], az = w1z[k4], an = w1n[k4];
            float4 br = w2r[k4], bz = w2z[k4], bn = w2n[k4];
            #pragma unroll
            for (int b = 0; b < BT; ++b) {
                float4 u = *(const float4*)(&h0s[b][k4 * 4]);
                float4 v = *(const float4*)(&h1s[b][k4 * 4]);
                bR[b]  += u.x * ar.x + u.y * ar.y + u.z * ar.z + u.w * ar.w
                        + v.x * br.x + v.y * br.y + v.z * br.z + v.w * br.w;
                bZ[b]  += u.x * az.x + u.y * az.y + u.z * az.z + u.w * az.w
                        + v.x * bz.x + v.y * bz.y + v.z * bz.z + v.w * bz.w;
                bNi[b] += u.x * an.x + u.y * an.y + u.z * an.z + u.w * an.w;
                bNh[b] += v.x * bn.x + v.y * bn.y + v.z * bn.z + v.w * bn.w;
            }
        }
        __syncthreads();   // all reads of old h1 complete

        #pragma unroll
        for (int b = 0; b < BT; ++b) {
            float r = sigmoidf_(bR[b]);
            float z = sigmoidf_(bZ[b]);
            float n = tanhf(bNi[b] + r * bNh[b]);
            h1s[b][t] = (1.f - z) * n + z * h1s[b][t];
        }
        __syncthreads();   // new h1 visible

        // ---------------- logits + sampling-state update ----------------
        if (t < BT) {
            float l0 = bl0, l1 = bl1;
            for (int k = 0; k < HH; ++k) {
                float hv = h1s[t][k];
                l0 += hv * wls[k];
                l1 += hv * wls[HH + k];
            }

            bool  ev  = (step & 1) == 0;
            float low = -16.f + (float)(step >> 1);   // baseline=-16, + step//2
            float cnt = ev ? nup : ndn;
            float mocc = (16.f > cnt) ? 1.f : 0.f;    // component 1
            float mun  = (low  < cnt) ? 1.f : 0.f;    // component 0

            float mx = fmaxf(l0, l1);
            float e0 = expf(l0 - mx), e1 = expf(l1 - mx);
            float inv = 1.f / (e0 + e1);
            float a0 = sqrtf(e0 * inv) * mun;
            float a1 = sqrtf(e1 * inv) * mocc;
            float nrm = sqrtf(a0 * a0 + a1 * a1);
            float den = fmaxf(nrm, 1e-12f);
            a0 /= den; a1 /= den;

            const float PI_F = 3.14159265358979323846f;
            float p0 = PI_F * l0 / (1.f + fabsf(l0));
            float p1 = PI_F * l1 / (1.f + fabsf(l1));

            int bit = bitsS[t][step];
            amp *= bit ? a1 : a0;
            ph  += bit ? p1 : p0;
            if (ev) nup += (float)bit; else ndn += (float)bit;
        }
        __syncthreads();
    }

    // out_size = 4096 floats: the real part of wf per batch row.
    if (t < BT) {
        out[row0 + t] = amp * cosf(ph);
    }
}

extern "C" void kernel_launch(void* const* d_in, const int* in_sizes, int n_in,
                              void* d_out, int out_size, void* d_ws, size_t ws_size,
                              hipStream_t stream) {
    (void)in_sizes; (void)n_in; (void)out_size; (void)d_ws; (void)ws_size;
    const int*   x    = (const int*)d_in[0];
    const float* Wih0 = (const float*)d_in[1];
    const float* Whh0 = (const float*)d_in[2];
    const float* Wih1 = (const float*)d_in[3];
    const float* Whh1 = (const float*)d_in[4];
    const float* Wl   = (const float*)d_in[5];
    const float* bl   = (const float*)d_in[6];
    float* out = (float*)d_out;

    rnn_persist<<<BB / BT, NT, 0, stream>>>(x, Wih0, Whh0, Wih1, Whh1, Wl, bl, out);
}

// Round 6
// 8807.210 us; speedup vs baseline: 1.1817x; 1.1817x over previous
//
#include <hip/hip_runtime.h>
#include <math.h>

// Problem constants: B=4096, SORB=64, H=256, NELE=32 (alpha=16), 2 GRU layers
#define BB 4096
#define SS 64
#define HH 256
#define BT 16     // batch rows per WG -> 256 WGs, 1/CU
#define NT 256    // 4 waves; wave w owns hidden units [64w, 64w+64)
#define HPAD 257  // LDS row stride (odd -> 2-way-free banks for frag reads)

typedef __attribute__((ext_vector_type(8))) _Float16 half8;
typedef __attribute__((ext_vector_type(4))) float    f32x4;

__device__ __forceinline__ float sigmoidf_(float v){ return 1.0f/(1.0f+expf(-v)); }

// ---- prologue: pack W into MFMA-B-fragment blocks (fp16 hi + fp16 lo) ----
// mats: 0=Whh0, 1=Wih1, 2=Whh1 (each (768,256) row-major).
// block(mat,nt,kt) = 1024 halfs: hi[lane*8+j] = fp16(W[g][k]), lo at +512,
// with g = nt*16 + (lane&15), k = kt*32 + (lane>>4)*8 + j.
__global__ void pack_w(const float* __restrict__ Whh0, const float* __restrict__ Wih1,
                       const float* __restrict__ Whh1, _Float16* __restrict__ dst){
    int tid = blockIdx.x*blockDim.x + threadIdx.x;     // [0, 3*48*8*64)
    if (tid >= 3*48*8*64) return;
    int lane = tid & 63;
    int kt   = (tid>>6) & 7;
    int nt   = (tid>>9) % 48;
    int mat  = tid / (48*8*64);
    const float* W = (mat==0) ? Whh0 : (mat==1) ? Wih1 : Whh1;
    int g  = nt*16 + (lane & 15);
    int kb = kt*32 + (lane>>4)*8;
    _Float16* hp = dst + (((mat*48 + nt)*8 + kt) << 10) + lane*8;
    _Float16* lp = hp + 512;
    #pragma unroll
    for (int j=0;j<8;++j){
        float w = W[g*HH + kb + j];
        _Float16 hi = (_Float16)w;
        _Float16 lo = (_Float16)(w - (float)hi);
        hp[j] = hi; lp[j] = lo;
    }
}

// ---- main persistent kernel ----
__global__ __launch_bounds__(NT,1) void rnn_mfma(
    const int*      __restrict__ x,      // (B,S) in {-1,+1}
    const float*    __restrict__ Wih0,   // (768,2)
    const _Float16* __restrict__ wpk_h,  // packed weights (d_ws)
    const float*    __restrict__ Wl,     // (2,256)
    const float*    __restrict__ bl,     // (2,)
    float*          __restrict__ out)    // (B,) = real(wf)
{
    __shared__ float h0s[BT*HPAD];
    __shared__ float h1s[BT*HPAD];
    __shared__ float wls[2*HH];
    __shared__ float red[BT][17][2];
    __shared__ int   bitsS[BT][SS];

    const int t    = threadIdx.x;
    const int L    = t & 63;
    const int w    = t >> 6;       // wave id 0..3
    const int lm   = L & 15;       // MFMA: A-row m / B-col n / D-col n
    const int quad = L >> 4;       // MFMA: k-quad / D-row group
    const int row0 = blockIdx.x * BT;
    const half8* wpk = (const half8*)wpk_h;

    for (int i=t;i<BT*HPAD;i+=NT){ h0s[i]=0.f; h1s[i]=0.f; }
    for (int i=t;i<2*HH;i+=NT) wls[i]=Wl[i];
    for (int i=t;i<BT*SS;i+=NT){ int b=i/SS,s=i-b*SS; bitsS[b][s]=(x[(row0+b)*SS+s]>0)?1:0; }

    // layer-0 input-gate weights for this lane's 4 owned units (u = 16*(4w+q)+lm)
    float g0w[4][6];
    #pragma unroll
    for (int q=0;q<4;++q){
        int u = 16*(4*w+q) + lm;
        g0w[q][0]=Wih0[u*2+0];        g0w[q][1]=Wih0[u*2+1];
        g0w[q][2]=Wih0[(u+HH)*2+0];   g0w[q][3]=Wih0[(u+HH)*2+1];
        g0w[q][4]=Wih0[(u+2*HH)*2+0]; g0w[q][5]=Wih0[(u+2*HH)*2+1];
    }
    // persistent register copies of owned h-elements: [q][reg] at (m=quad*4+reg, u)
    float hr0[4][4] = {};
    float hr1[4][4] = {};
    float amp=1.f, ph=0.f, nup=0.f, ndn=0.f;
    const float bl0=bl[0], bl1=bl[1];

    __syncthreads();

    for (int step=0; step<SS; ++step){
        // ---------------- GEMM0: gh0 = h0 @ Whh0^T ----------------
        f32x4 acc0[12] = {};   // [type*4+q], type 0=r,1=z,2=n
        for (int kt=0; kt<8; ++kt){
            const float* hp = h0s + lm*HPAD + kt*32 + quad*8;
            half8 A;
            #pragma unroll
            for (int j=0;j<8;++j) A[j] = (_Float16)hp[j];
            #pragma unroll
            for (int type=0; type<3; ++type){
                #pragma unroll
                for (int q=0;q<4;++q){
                    int nt = type*16 + 4*w + q;
                    const half8* bp = wpk + ((nt*8 + kt) << 7);   // mat 0
                    half8 bh = bp[L], blo = bp[64+L];
                    acc0[type*4+q] = __builtin_amdgcn_mfma_f32_16x16x32_f16(A, bh,  acc0[type*4+q],0,0,0);
                    acc0[type*4+q] = __builtin_amdgcn_mfma_f32_16x16x32_f16(A, blo, acc0[type*4+q],0,0,0);
                }
            }
        }
        __syncthreads();   // all waves done reading h0s

        // ---------------- elementwise 0 (in registers) ----------------
        #pragma unroll
        for (int q=0;q<4;++q){
            int u = 16*(4*w+q) + lm;
            #pragma unroll
            for (int reg=0;reg<4;++reg){
                int m = quad*4 + reg;
                float gr=0.f,gz=0.f,gn=0.f;
                if (step>0){
                    int c = bitsS[m][step-1];
                    gr = c?g0w[q][1]:g0w[q][0];
                    gz = c?g0w[q][3]:g0w[q][2];
                    gn = c?g0w[q][5]:g0w[q][4];
                }
                float r = sigmoidf_(gr + acc0[q][reg]);
                float z = sigmoidf_(gz + acc0[4+q][reg]);
                float n = tanhf(gn + r*acc0[8+q][reg]);
                float hnew = (1.f-z)*n + z*hr0[q][reg];
                hr0[q][reg] = hnew;
                h0s[m*HPAD + u] = hnew;
            }
        }
        __syncthreads();   // h0n visible

        // ---------------- GEMM1: gi1 = h0n@Wih1^T ; gh1 = h1@Whh1^T ----------------
        f32x4 accRZ[8] = {};   // r: [q], z: [4+q] (i+h fused)
        f32x4 accNI[4] = {};   // n-gate input part
        f32x4 accNH[4] = {};   // n-gate hidden part
        for (int kt=0; kt<8; ++kt){
            const float* p0 = h0s + lm*HPAD + kt*32 + quad*8;
            const float* p1 = h1s + lm*HPAD + kt*32 + quad*8;
            half8 A0, A1;
            #pragma unroll
            for (int j=0;j<8;++j){ A0[j]=(_Float16)p0[j]; A1[j]=(_Float16)p1[j]; }
            #pragma unroll
            for (int q=0;q<4;++q){
                int ntr = 4*w+q, ntz = 16+4*w+q, ntn = 32+4*w+q;
                const half8* bir = wpk + (((48+ntr)*8 + kt) << 7);    // mat1, r
                const half8* bhr = wpk + (((96+ntr)*8 + kt) << 7);    // mat2, r
                accRZ[q] = __builtin_amdgcn_mfma_f32_16x16x32_f16(A0, bir[L],    accRZ[q],0,0,0);
                accRZ[q] = __builtin_amdgcn_mfma_f32_16x16x32_f16(A0, bir[64+L], accRZ[q],0,0,0);
                accRZ[q] = __builtin_amdgcn_mfma_f32_16x16x32_f16(A1, bhr[L],    accRZ[q],0,0,0);
                accRZ[q] = __builtin_amdgcn_mfma_f32_16x16x32_f16(A1, bhr[64+L], accRZ[q],0,0,0);
                const half8* biz = wpk + (((48+ntz)*8 + kt) << 7);
                const half8* bhz = wpk + (((96+ntz)*8 + kt) << 7);
                accRZ[4+q] = __builtin_amdgcn_mfma_f32_16x16x32_f16(A0, biz[L],    accRZ[4+q],0,0,0);
                accRZ[4+q] = __builtin_amdgcn_mfma_f32_16x16x32_f16(A0, biz[64+L], accRZ[4+q],0,0,0);
                accRZ[4+q] = __builtin_amdgcn_mfma_f32_16x16x32_f16(A1, bhz[L],    accRZ[4+q],0,0,0);
                accRZ[4+q] = __builtin_amdgcn_mfma_f32_16x16x32_f16(A1, bhz[64+L], accRZ[4+q],0,0,0);
                const half8* bin = wpk + (((48+ntn)*8 + kt) << 7);
                const half8* bhn = wpk + (((96+ntn)*8 + kt) << 7);
                accNI[q] = __builtin_amdgcn_mfma_f32_16x16x32_f16(A0, bin[L],    accNI[q],0,0,0);
                accNI[q] = __builtin_amdgcn_mfma_f32_16x16x32_f16(A0, bin[64+L], accNI[q],0,0,0);
                accNH[q] = __builtin_amdgcn_mfma_f32_16x16x32_f16(A1, bhn[L],    accNH[q],0,0,0);
                accNH[q] = __builtin_amdgcn_mfma_f32_16x16x32_f16(A1, bhn[64+L], accNH[q],0,0,0);
            }
        }
        __syncthreads();   // all waves done reading h0s/h1s

        // ---------------- elementwise 1 ----------------
        #pragma unroll
        for (int q=0;q<4;++q){
            int u = 16*(4*w+q) + lm;
            #pragma unroll
            for (int reg=0;reg<4;++reg){
                int m = quad*4 + reg;
                float r = sigmoidf_(accRZ[q][reg]);
                float z = sigmoidf_(accRZ[4+q][reg]);
                float n = tanhf(accNI[q][reg] + r*accNH[q][reg]);
                float hnew = (1.f-z)*n + z*hr1[q][reg];
                hr1[q][reg] = hnew;
                h1s[m*HPAD + u] = hnew;
            }
        }
        __syncthreads();   // h1n visible

        // ---------------- logits partials (all 256 threads) ----------------
        {
            int b = t>>4, seg = t&15;
            float s0=0.f, s1=0.f;
            #pragma unroll
            for (int j=0;j<16;++j){
                float hv = h1s[b*HPAD + seg*16 + j];
                s0 += hv*wls[seg*16+j];
                s1 += hv*wls[HH+seg*16+j];
            }
            red[b][seg][0]=s0; red[b][seg][1]=s1;
        }
        __syncthreads();

        // ---------------- finalize sampling state (t<16) ----------------
        if (t < BT){
            float l0=bl0, l1=bl1;
            #pragma unroll
            for (int s2=0;s2<16;++s2){ l0+=red[t][s2][0]; l1+=red[t][s2][1]; }

            bool  ev  = (step & 1) == 0;
            float low = -16.f + (float)(step>>1);
            float cnt = ev ? nup : ndn;
            float mocc = (16.f > cnt) ? 1.f : 0.f;
            float mun  = (low  < cnt) ? 1.f : 0.f;

            float mx = fmaxf(l0,l1);
            float e0 = expf(l0-mx), e1 = expf(l1-mx);
            float inv = 1.f/(e0+e1);
            float a0 = sqrtf(e0*inv)*mun;
            float a1 = sqrtf(e1*inv)*mocc;
            float nrm = sqrtf(a0*a0+a1*a1);
            float den = fmaxf(nrm, 1e-12f);
            a0/=den; a1/=den;

            const float PI_F = 3.14159265358979323846f;
            float p0 = PI_F*l0/(1.f+fabsf(l0));
            float p1 = PI_F*l1/(1.f+fabsf(l1));

            int bit = bitsS[t][step];
            amp *= bit ? a1 : a0;
            ph  += bit ? p1 : p0;
            if (ev) nup += (float)bit; else ndn += (float)bit;
        }
        // no barrier needed: next phases touching red/h are >=2 barriers away
    }

    if (t < BT) out[row0 + t] = amp * cosf(ph);
}

extern "C" void kernel_launch(void* const* d_in, const int* in_sizes, int n_in,
                              void* d_out, int out_size, void* d_ws, size_t ws_size,
                              hipStream_t stream) {
    (void)in_sizes; (void)n_in; (void)out_size; (void)ws_size;
    const int*   x    = (const int*)d_in[0];
    const float* Wih0 = (const float*)d_in[1];
    const float* Whh0 = (const float*)d_in[2];
    const float* Wih1 = (const float*)d_in[3];
    const float* Whh1 = (const float*)d_in[4];
    const float* Wl   = (const float*)d_in[5];
    const float* bl   = (const float*)d_in[6];
    float* out = (float*)d_out;
    _Float16* wpk = (_Float16*)d_ws;   // 3*48*8*1024 halfs = 2,359,296 B

    pack_w<<<(3*48*8*64 + 255)/256, 256, 0, stream>>>(Whh0, Wih1, Whh1, wpk);
    rnn_mfma<<<BB/BT, NT, 0, stream>>>(x, Wih0, wpk, Wl, bl, out);
}

// Round 7
// 2655.626 us; speedup vs baseline: 3.9191x; 3.3164x over previous
//
#include <hip/hip_runtime.h>
#include <math.h>

// Problem constants: B=4096, SORB=64, H=256, NELE=32 (alpha=16), 2 GRU layers
#define BB 4096
#define SS 64
#define HH 256
#define BT 32      // batch rows per WG -> 128 WGs (each on its own CU; VGPR caps 1 WG/CU)
#define NT 512     // 8 waves; wave w owns hidden units [32w, 32w+32) per gate type
#define HPADH 264  // LDS h row stride in halfs (528 B: 16B-aligned, 2-way-free banks)

typedef __attribute__((ext_vector_type(8))) _Float16 half8;
typedef __attribute__((ext_vector_type(4))) float    f32x4;

__device__ __forceinline__ float sigmoidf_(float v){ return 1.0f/(1.0f+expf(-v)); }

// ---- prologue: pack W into MFMA-B-fragment blocks (fp16, hi only) ----
// mats: 0=Whh0, 1=Wih1, 2=Whh1 (each (768,256) row-major).
// block(mat,nt,kt) = 512 halfs: [lane*8+j] = fp16(W[g][k]),
// g = nt*16 + (lane&15), k = kt*32 + (lane>>4)*8 + j.   (B[k][n] = W^T[k][n])
__global__ void pack_w(const float* __restrict__ Whh0, const float* __restrict__ Wih1,
                       const float* __restrict__ Whh1, _Float16* __restrict__ dst){
    int tid = blockIdx.x*blockDim.x + threadIdx.x;     // [0, 3*48*8*64)
    if (tid >= 3*48*8*64) return;
    int lane = tid & 63;
    int kt   = (tid>>6) & 7;
    int nt   = (tid>>9) % 48;
    int mat  = tid / (48*8*64);
    const float* W = (mat==0) ? Whh0 : (mat==1) ? Wih1 : Whh1;
    int g  = nt*16 + (lane & 15);
    int kb = kt*32 + (lane>>4)*8;
    _Float16* hp = dst + (((mat*48 + nt)*8 + kt) << 9) + lane*8;
    #pragma unroll
    for (int j=0;j<8;++j) hp[j] = (_Float16)W[g*HH + kb + j];
}

// ---- main persistent kernel ----
__global__ __launch_bounds__(NT,2) void rnn_mfma(
    const int*      __restrict__ x,      // (B,S) in {-1,+1}
    const float*    __restrict__ Wih0,   // (768,2)
    const _Float16* __restrict__ wpk_h,  // packed fp16 weights (d_ws)
    const float*    __restrict__ Wl,     // (2,256)
    const float*    __restrict__ bl,     // (2,)
    float*          __restrict__ out)    // (B,) = real(wf)
{
    __shared__ _Float16 h0h[BT*HPADH];
    __shared__ _Float16 h1h[BT*HPADH];
    __shared__ float    wls[2*HH];
    __shared__ float    red[BT][17][2];
    __shared__ int      bitsS[BT][SS];

    const int t    = threadIdx.x;
    const int L    = t & 63;
    const int w    = t >> 6;       // wave id 0..7
    const int lm   = L & 15;       // MFMA: A-row m / B-col n / D-col n
    const int quad = L >> 4;       // MFMA: k-octet / D-row group
    const int row0 = blockIdx.x * BT;
    const half8* wpk = (const half8*)wpk_h;
    #define M1OFF (48*8*64)
    #define M2OFF (96*8*64)

    for (int i=t;i<BT*HPADH;i+=NT){ h0h[i]=(_Float16)0.f; h1h[i]=(_Float16)0.f; }
    for (int i=t;i<2*HH;i+=NT) wls[i]=Wl[i];
    for (int i=t;i<BT*SS;i+=NT){ int b=i>>6,s=i&63; bitsS[b][s]=(x[(row0+b)*SS+s]>0)?1:0; }

    // layer-0 input-gate weights for this lane's 2 owned units (u = 16*(2w+q)+lm)
    float g0w[2][6];
    #pragma unroll
    for (int q=0;q<2;++q){
        int u = 16*(2*w+q) + lm;
        g0w[q][0]=Wih0[u*2+0];        g0w[q][1]=Wih0[u*2+1];
        g0w[q][2]=Wih0[(u+HH)*2+0];   g0w[q][3]=Wih0[(u+HH)*2+1];
        g0w[q][4]=Wih0[(u+2*HH)*2+0]; g0w[q][5]=Wih0[(u+2*HH)*2+1];
    }
    // persistent fp32 copies of owned h: [q][mt][reg] at (m=mt*16+quad*4+reg, u)
    float hr0[2][2][4] = {};
    float hr1[2][2][4] = {};
    float amp=1.f, ph=0.f, nup=0.f, ndn=0.f;
    const float bl0=bl[0], bl1=bl[1];

    __syncthreads();

    for (int step=0; step<SS; ++step){
        // ---------------- GEMM0: gh0 = h0 @ Whh0^T ----------------
        f32x4 acc0[3][2][2] = {};    // [type][q][mtile]
        for (int kt=0; kt<8; ++kt){
            half8 A[2];
            #pragma unroll
            for (int mt=0;mt<2;++mt)
                A[mt] = *(const half8*)(h0h + (mt*16+lm)*HPADH + kt*32 + quad*8);
            #pragma unroll
            for (int type=0; type<3; ++type){
                #pragma unroll
                for (int q=0;q<2;++q){
                    int nt = type*16 + 2*w + q;
                    half8 Bv = wpk[(nt*8 + kt)*64 + L];
                    #pragma unroll
                    for (int mt=0;mt<2;++mt)
                        acc0[type][q][mt] = __builtin_amdgcn_mfma_f32_16x16x32_f16(A[mt], Bv, acc0[type][q][mt],0,0,0);
                }
            }
        }
        __syncthreads();   // all waves done reading h0h

        // ---------------- elementwise 0 (registers) ----------------
        #pragma unroll
        for (int q=0;q<2;++q){
            int u = 16*(2*w+q) + lm;
            #pragma unroll
            for (int mt=0;mt<2;++mt){
                #pragma unroll
                for (int reg=0;reg<4;++reg){
                    int m = mt*16 + quad*4 + reg;
                    float gr=0.f,gz=0.f,gn=0.f;
                    if (step>0){
                        int c = bitsS[m][step-1];
                        gr = c?g0w[q][1]:g0w[q][0];
                        gz = c?g0w[q][3]:g0w[q][2];
                        gn = c?g0w[q][5]:g0w[q][4];
                    }
                    float r = sigmoidf_(gr + acc0[0][q][mt][reg]);
                    float z = sigmoidf_(gz + acc0[1][q][mt][reg]);
                    float n = tanhf(gn + r*acc0[2][q][mt][reg]);
                    float hnew = (1.f-z)*n + z*hr0[q][mt][reg];
                    hr0[q][mt][reg] = hnew;
                    h0h[m*HPADH + u] = (_Float16)hnew;
                }
            }
        }
        __syncthreads();   // h0n visible

        // ------- GEMM1: gi1 = h0n@Wih1^T ; gh1 = h1@Whh1^T -------
        f32x4 aR[2][2]={}, aZ[2][2]={}, aNI[2][2]={}, aNH[2][2]={};
        for (int kt=0; kt<8; ++kt){
            half8 A0[2], A1[2];
            #pragma unroll
            for (int mt=0;mt<2;++mt){
                A0[mt] = *(const half8*)(h0h + (mt*16+lm)*HPADH + kt*32 + quad*8);
                A1[mt] = *(const half8*)(h1h + (mt*16+lm)*HPADH + kt*32 + quad*8);
            }
            #pragma unroll
            for (int q=0;q<2;++q){
                int ntr = 2*w+q, ntz = 16+2*w+q, ntn = 32+2*w+q;
                half8 bir = wpk[M1OFF + (ntr*8+kt)*64 + L];
                half8 bhr = wpk[M2OFF + (ntr*8+kt)*64 + L];
                half8 biz = wpk[M1OFF + (ntz*8+kt)*64 + L];
                half8 bhz = wpk[M2OFF + (ntz*8+kt)*64 + L];
                half8 bin = wpk[M1OFF + (ntn*8+kt)*64 + L];
                half8 bhn = wpk[M2OFF + (ntn*8+kt)*64 + L];
                #pragma unroll
                for (int mt=0;mt<2;++mt){
                    aR[q][mt]  = __builtin_amdgcn_mfma_f32_16x16x32_f16(A0[mt], bir, aR[q][mt],0,0,0);
                    aR[q][mt]  = __builtin_amdgcn_mfma_f32_16x16x32_f16(A1[mt], bhr, aR[q][mt],0,0,0);
                    aZ[q][mt]  = __builtin_amdgcn_mfma_f32_16x16x32_f16(A0[mt], biz, aZ[q][mt],0,0,0);
                    aZ[q][mt]  = __builtin_amdgcn_mfma_f32_16x16x32_f16(A1[mt], bhz, aZ[q][mt],0,0,0);
                    aNI[q][mt] = __builtin_amdgcn_mfma_f32_16x16x32_f16(A0[mt], bin, aNI[q][mt],0,0,0);
                    aNH[q][mt] = __builtin_amdgcn_mfma_f32_16x16x32_f16(A1[mt], bhn, aNH[q][mt],0,0,0);
                }
            }
        }
        __syncthreads();   // all waves done reading h0h/h1h

        // ---------------- elementwise 1 ----------------
        #pragma unroll
        for (int q=0;q<2;++q){
            int u = 16*(2*w+q) + lm;
            #pragma unroll
            for (int mt=0;mt<2;++mt){
                #pragma unroll
                for (int reg=0;reg<4;++reg){
                    int m = mt*16 + quad*4 + reg;
                    float r = sigmoidf_(aR[q][mt][reg]);
                    float z = sigmoidf_(aZ[q][mt][reg]);
                    float n = tanhf(aNI[q][mt][reg] + r*aNH[q][mt][reg]);
                    float hnew = (1.f-z)*n + z*hr1[q][mt][reg];
                    hr1[q][mt][reg] = hnew;
                    h1h[m*HPADH + u] = (_Float16)hnew;
                }
            }
        }
        __syncthreads();   // h1n visible

        // ---------------- logits partials (all 512 threads) ----------------
        {
            int b = t>>4, seg = t&15;
            float s0=0.f, s1=0.f;
            #pragma unroll
            for (int j=0;j<16;++j){
                float hv = (float)h1h[b*HPADH + seg*16 + j];
                s0 += hv*wls[seg*16+j];
                s1 += hv*wls[HH+seg*16+j];
            }
            red[b][seg][0]=s0; red[b][seg][1]=s1;
        }
        __syncthreads();

        // ---------------- finalize sampling state (t<32) ----------------
        if (t < BT){
            float l0=bl0, l1=bl1;
            #pragma unroll
            for (int s2=0;s2<16;++s2){ l0+=red[t][s2][0]; l1+=red[t][s2][1]; }

            bool  ev  = (step & 1) == 0;
            float low = -16.f + (float)(step>>1);
            float cnt = ev ? nup : ndn;
            float mocc = (16.f > cnt) ? 1.f : 0.f;
            float mun  = (low  < cnt) ? 1.f : 0.f;

            float mx = fmaxf(l0,l1);
            float e0 = expf(l0-mx), e1 = expf(l1-mx);
            float inv = 1.f/(e0+e1);
            float a0 = sqrtf(e0*inv)*mun;
            float a1 = sqrtf(e1*inv)*mocc;
            float nrm = sqrtf(a0*a0+a1*a1);
            float den = fmaxf(nrm, 1e-12f);
            a0/=den; a1/=den;

            const float PI_F = 3.14159265358979323846f;
            float p0 = PI_F*l0/(1.f+fabsf(l0));
            float p1 = PI_F*l1/(1.f+fabsf(l1));

            int bit = bitsS[t][step];
            amp *= bit ? a1 : a0;
            ph  += bit ? p1 : p0;
            if (ev) nup += (float)bit; else ndn += (float)bit;
        }
        // next phase touching red/h is >=2 barriers away
    }

    if (t < BT) out[row0 + t] = amp * cosf(ph);
}

extern "C" void kernel_launch(void* const* d_in, const int* in_sizes, int n_in,
                              void* d_out, int out_size, void* d_ws, size_t ws_size,
                              hipStream_t stream) {
    (void)in_sizes; (void)n_in; (void)out_size; (void)ws_size;
    const int*   x    = (const int*)d_in[0];
    const float* Wih0 = (const float*)d_in[1];
    const float* Whh0 = (const float*)d_in[2];
    const float* Wih1 = (const float*)d_in[3];
    const float* Whh1 = (const float*)d_in[4];
    const float* Wl   = (const float*)d_in[5];
    const float* bl   = (const float*)d_in[6];
    float* out = (float*)d_out;
    _Float16* wpk = (_Float16*)d_ws;   // 3*48*8*512 halfs = 1,179,648 B

    pack_w<<<(3*48*8*64 + 255)/256, 256, 0, stream>>>(Whh0, Wih1, Whh1, wpk);
    rnn_mfma<<<BB/BT, NT, 0, stream>>>(x, Wih0, wpk, Wl, bl, out);
}